// Round 8
// baseline (139.185 us; speedup 1.0000x reference)
//
#include <hip/hip_runtime.h>
#include <hip/hip_bf16.h>

#define B_TOT   4096
#define T_STEPS 256
#define IN_D    28
#define HID     128
#define OUT_D   784
#define BM      16

typedef __bf16 bf16x8 __attribute__((ext_vector_type(8)));
typedef __bf16 bf16x4 __attribute__((ext_vector_type(4)));
typedef float  f32x4  __attribute__((ext_vector_type(4)));

__device__ __forceinline__ float bf2f(__bf16 b) {
    unsigned short s = __builtin_bit_cast(unsigned short, b);
    unsigned int u = ((unsigned int)s) << 16;
    return __builtin_bit_cast(float, u);
}

// H LDS layout: [16 rows b][128 bf16 n] = 256 B/row, XOR-swizzled so the
// 16-lane b128 read groups land 2-way (free, m136) instead of 16-way.
__device__ __forceinline__ int hswz(int row, int byteInRow) {
    return row * 256 + (byteInRow ^ ((row & 7) << 4));
}

// Raw barrier: drains LDS ops only. Does NOT drain vmcnt -> in-flight global
// x prefetch loads survive the barrier (the whole point; __syncthreads would
// wait for them every step = 1 HBM round-trip per step).
#define BAR() asm volatile("s_waitcnt lgkmcnt(0)\n\ts_barrier" ::: "memory")

__global__ __launch_bounds__(256) void rnn_fused(
    const float* __restrict__ x,     // [B,T,IN] f32
    const float* __restrict__ h0,    // [B,HID] f32
    const float* __restrict__ W_ih,  // [HID,IN] f32
    const float* __restrict__ b_ih,  // [HID] f32
    const float* __restrict__ W_hh,  // [HID,HID] f32
    const float* __restrict__ b_hh,  // [HID] f32
    const float* __restrict__ W_ho,  // [OUT_D,HID] f32
    const float* __restrict__ b_ho,  // [OUT_D] f32
    float* __restrict__ out)         // [B*OUT_D] f32, then [B*HID] f32
{
    __shared__ __align__(16) unsigned char Hb[2][BM * 256]; // h (bf16) double buffer

    const int tid  = threadIdx.x;
    const int lane = tid & 63;
    const int wv   = tid >> 6;       // wave 0..3
    const int ln15 = lane & 15;
    const int lg   = lane >> 4;      // k-group 0..3
    const int b0   = blockIdx.x * BM;

    // ---- Weight fragments (f32 -> bf16), register-resident, MFMA *A* operand:
    // A[m = n_out][k], lane: m = nt + ln15, k = 8*lg + e.
    const int nt0 = wv * 32;         // this wave owns hidden cols [nt0, nt0+32)
    bf16x8 bw[2][4];
    #pragma unroll
    for (int ti = 0; ti < 2; ++ti) {
        int n = nt0 + ti * 16 + ln15;
        #pragma unroll
        for (int kc = 0; kc < 4; ++kc) {
            const float* p = W_hh + n * HID + kc * 32 + lg * 8;
            bf16x8 v;
            #pragma unroll
            for (int e = 0; e < 8; ++e) v[e] = (__bf16)p[e];
            bw[ti][kc] = v;
        }
    }
    const __bf16 bzero = (__bf16)0.0f;
    bf16x8 bxf[2];
    #pragma unroll
    for (int ti = 0; ti < 2; ++ti) {
        int n = nt0 + ti * 16 + ln15;
        bf16x8 v;
        #pragma unroll
        for (int e = 0; e < 8; ++e) {
            int k = lg * 8 + e;
            v[e] = (k < IN_D) ? (__bf16)W_ih[n * IN_D + k] : bzero;  // zero-pad K 28->32
        }
        bxf[ti] = v;
    }
    // bias per lane: D row = n_out = nt0 + ti*16 + 4*lg + r  (4 consecutive)
    f32x4 bias4[2];
    #pragma unroll
    for (int ti = 0; ti < 2; ++ti) {
        int n = nt0 + ti * 16 + 4 * lg;
        f32x4 bi = *(const f32x4*)(b_ih + n);
        f32x4 bh = *(const f32x4*)(b_hh + n);
        bias4[ti] = bi + bh;
    }

    // ---- stage initial hidden into Hb[0] (f32 -> bf16)
    {
        int row = tid >> 4, cg = tid & 15;
        const float* p = h0 + (size_t)(b0 + row) * HID + cg * 8;
        bf16x8 hv;
        #pragma unroll
        for (int e = 0; e < 8; ++e) hv[e] = (__bf16)p[e];
        *(bf16x8*)(&Hb[0][hswz(row, cg * 16)]) = hv;
    }

    // ---- per-lane x fragment pointers (each lane owns its own x data; the
    // 4 waves read the same lines -> L2 hits). lg=3's upper half (k=28..31)
    // is clamped to k=24..27: values are killed by the zero-padded W_ih frag.
    const float* xlane  = x + (size_t)(b0 + ln15) * T_STEPS * IN_D + lg * 8;
    const float* xlane2 = x + (size_t)(b0 + ln15) * T_STEPS * IN_D + (lg == 3 ? 24 : lg * 8 + 4);
    // register ring, depth 4 (statically indexed, rule #20)
    f32x4 q0a = *(const f32x4*)(xlane  + 0 * IN_D), q0b = *(const f32x4*)(xlane2 + 0 * IN_D);
    f32x4 q1a = *(const f32x4*)(xlane  + 1 * IN_D), q1b = *(const f32x4*)(xlane2 + 1 * IN_D);
    f32x4 q2a = *(const f32x4*)(xlane  + 2 * IN_D), q2b = *(const f32x4*)(xlane2 + 2 * IN_D);
    f32x4 q3a = *(const f32x4*)(xlane  + 3 * IN_D), q3b = *(const f32x4*)(xlane2 + 3 * IN_D);

    BAR();  // Hb[0] visible; x loads stay in flight

    // ================= recurrence: 256 steps, 1 raw barrier/step =============
    // Transposed MFMA: D[n_out][batch] = W * h^T. A = weight frag (regs),
    // B = h frag (b128 from LDS) / x frag (regs). Lane holds batch=ln15,
    // n_out = nt + 4lg + r -> one ds_write_b64 per ti.
#define STEP(T, QA, QB)                                                         \
    {                                                                           \
        const int rb = (T) & 1;                                                 \
        bf16x8 ah0 = *(const bf16x8*)(&Hb[rb][hswz(ln15,   0 + lg * 16)]);      \
        bf16x8 ah1 = *(const bf16x8*)(&Hb[rb][hswz(ln15,  64 + lg * 16)]);      \
        bf16x8 ah2 = *(const bf16x8*)(&Hb[rb][hswz(ln15, 128 + lg * 16)]);      \
        bf16x8 ah3 = *(const bf16x8*)(&Hb[rb][hswz(ln15, 192 + lg * 16)]);      \
        bf16x8 ax;                                                              \
        _Pragma("unroll")                                                       \
        for (int e = 0; e < 4; ++e) { ax[e] = (__bf16)QA[e]; ax[4 + e] = (__bf16)QB[e]; } \
        f32x4 a0 = __builtin_amdgcn_mfma_f32_16x16x32_bf16(bxf[0], ax, bias4[0], 0, 0, 0); \
        f32x4 a1 = __builtin_amdgcn_mfma_f32_16x16x32_bf16(bxf[1], ax, bias4[1], 0, 0, 0); \
        if ((T) + 4 < T_STEPS) {                                                \
            QA = *(const f32x4*)(xlane  + (size_t)((T) + 4) * IN_D);            \
            QB = *(const f32x4*)(xlane2 + (size_t)((T) + 4) * IN_D);            \
        }                                                                       \
        f32x4 z = {0.f, 0.f, 0.f, 0.f};                                         \
        a0 = __builtin_amdgcn_mfma_f32_16x16x32_bf16(bw[0][0], ah0, a0, 0, 0, 0); \
        a1 = __builtin_amdgcn_mfma_f32_16x16x32_bf16(bw[1][0], ah0, a1, 0, 0, 0); \
        f32x4 c0 = __builtin_amdgcn_mfma_f32_16x16x32_bf16(bw[0][1], ah1, z, 0, 0, 0); \
        f32x4 c1 = __builtin_amdgcn_mfma_f32_16x16x32_bf16(bw[1][1], ah1, z, 0, 0, 0); \
        a0 = __builtin_amdgcn_mfma_f32_16x16x32_bf16(bw[0][2], ah2, a0, 0, 0, 0); \
        a1 = __builtin_amdgcn_mfma_f32_16x16x32_bf16(bw[1][2], ah2, a1, 0, 0, 0); \
        c0 = __builtin_amdgcn_mfma_f32_16x16x32_bf16(bw[0][3], ah3, c0, 0, 0, 0); \
        c1 = __builtin_amdgcn_mfma_f32_16x16x32_bf16(bw[1][3], ah3, c1, 0, 0, 0); \
        _Pragma("unroll")                                                       \
        for (int ti = 0; ti < 2; ++ti) {                                        \
            f32x4 s = ti ? (a1 + c1) : (a0 + c0);                               \
            bf16x4 w;                                                           \
            _Pragma("unroll")                                                   \
            for (int r = 0; r < 4; ++r) {                                       \
                float v = s[r];                                                 \
                w[r] = (__bf16)(v > 0.f ? v : 0.f);                             \
            }                                                                   \
            *(bf16x4*)(&Hb[rb ^ 1][hswz(ln15, nt0 * 2 + ti * 32 + lg * 8)]) = w; \
        }                                                                       \
        BAR();                                                                  \
    }

    for (int t = 0; t < T_STEPS; t += 4) {
        STEP(t + 0, q0a, q0b)
        STEP(t + 1, q1a, q1b)
        STEP(t + 2, q2a, q2b)
        STEP(t + 3, q3a, q3b)
    }
#undef STEP
    // after t=255 (rb=1) the final h sits in Hb[0]; last BAR() makes it visible

    // ================= epilogue =================
    // h_final -> d_out second segment (f32)
    {
        int row = tid >> 4, cg = tid & 15;
        bf16x8 hv = *(const bf16x8*)(&Hb[0][hswz(row, cg * 16)]);
        float* po = out + (size_t)B_TOT * OUT_D + (size_t)(b0 + row) * HID + cg * 8;
        #pragma unroll
        for (int e = 0; e < 8; ++e) po[e] = bf2f(hv[e]);
    }
    // projection (transposed form): D[o][batch], A = W_ho frag, B = h frag.
    bf16x8 af[4];
    #pragma unroll
    for (int kc = 0; kc < 4; ++kc)
        af[kc] = *(const bf16x8*)(&Hb[0][hswz(ln15, kc * 64 + lg * 16)]);

    for (int nt = wv; nt < 49; nt += 4) {
        f32x4 acc = *(const f32x4*)(b_ho + nt * 16 + 4 * lg);
        #pragma unroll
        for (int kc = 0; kc < 4; ++kc) {
            const float* p = W_ho + (nt * 16 + ln15) * HID + kc * 32 + lg * 8;
            bf16x8 bfrag;
            #pragma unroll
            for (int e = 0; e < 8; ++e) bfrag[e] = (__bf16)p[e];
            acc = __builtin_amdgcn_mfma_f32_16x16x32_bf16(bfrag, af[kc], acc, 0, 0, 0);
        }
        // lane holds batch=ln15, o = nt*16 + 4lg + r -> one dwordx4 store
        *(f32x4*)(out + (size_t)(b0 + ln15) * OUT_D + nt * 16 + 4 * lg) = acc;
    }
}

extern "C" void kernel_launch(void* const* d_in, const int* in_sizes, int n_in,
                              void* d_out, int out_size, void* d_ws, size_t ws_size,
                              hipStream_t stream) {
    const float* x    = (const float*)d_in[0];
    const float* h0   = (const float*)d_in[1];
    const float* W_ih = (const float*)d_in[2];
    const float* b_ih = (const float*)d_in[3];
    const float* W_hh = (const float*)d_in[4];
    const float* b_hh = (const float*)d_in[5];
    const float* W_ho = (const float*)d_in[6];
    const float* b_ho = (const float*)d_in[7];
    rnn_fused<<<B_TOT / BM, 256, 0, stream>>>(x, h0, W_ih, b_ih, W_hh, b_hh,
                                              W_ho, b_ho, (float*)d_out);
}